// Round 1
// baseline (11120.365 us; speedup 1.0000x reference)
//
#include <hip/hip_runtime.h>
#include <hip/hip_bf16.h>
#include <stdint.h>

#define HID    1024
#define NSTEP  4096
#define NBLK   128
#define UPB    8      // units per block
#define THREADS 512   // 8 waves

// ---------------- ws layout ----------------
// [0, 16MiB)              W' = W_hh + W_ih @ W_dec   (4096 x 1024 f32)
// [16MiB, +16KiB)         b' = b_ih+b_hh+W_ih@b_dec  (4096 f32)
// [.. +16KiB)             ginit = W_ih@x + b_ih+b_hh (4096 f32)
// [.. +16KiB)             hbuf: 2 slots x 1024 x u64 {tag,val} pairs
// [16MiB+64KiB, +16MiB)   H history: 4096 x 1024 f32
// total ~32.1 MiB

__device__ __forceinline__ float d4(float4 a, float4 b) {
    return fmaf(a.x, b.x, fmaf(a.y, b.y, fmaf(a.z, b.z, a.w * b.w)));
}

// ---- prep: b', ginit, clear hbuf tags ----
__global__ void k_prep(const float* __restrict__ x, const float* __restrict__ Wih,
                       const float* __restrict__ bih, const float* __restrict__ bhh,
                       const float* __restrict__ bdec,
                       float* __restrict__ bp, float* __restrict__ gi,
                       unsigned long long* __restrict__ hbuf) {
    int i = blockIdx.x * 256 + threadIdx.x;
    if (i < 4096) {
        float base = bih[i] + bhh[i];
        float s_b = base, s_g = base;
#pragma unroll
        for (int d = 0; d < 11; ++d) {
            float w = Wih[i * 11 + d];
            s_b = fmaf(w, bdec[d], s_b);
            s_g = fmaf(w, x[d], s_g);
        }
        bp[i] = s_b;
        gi[i] = s_g;
    }
    int j = i - 4096;
    if (j >= 0 && j < 2048) hbuf[j] = 0ULL;   // clear step tags (both parity slots)
}

// ---- fold: W' = W_hh + W_ih @ W_dec ----
__global__ void k_fold(const float* __restrict__ Wih, const float* __restrict__ Whh,
                       const float* __restrict__ Wdec, float* __restrict__ Wp) {
    int idx = blockIdx.x * 256 + threadIdx.x;       // 0 .. 4M-1
    int r = idx >> 10, k = idx & 1023;
    float acc = Whh[idx];
#pragma unroll
    for (int d = 0; d < 11; ++d)
        acc = fmaf(Wih[r * 11 + d], Wdec[d * HID + k], acc);
    Wp[idx] = acc;
}

// ---- the sequential LSTM recurrence ----
__global__ __launch_bounds__(THREADS) void lstm_seq(
    const float* __restrict__ Wp, const float* __restrict__ bp,
    const float* __restrict__ gi, unsigned long long* hbuf,
    float* __restrict__ Hh) {
    const int tid  = threadIdx.x;
    const int wv   = tid >> 6;
    const int lane = tid & 63;
    const int unit = blockIdx.x * UPB + wv;

    // per-lane weights: 16 per gate (k = lane*16 .. lane*16+15), held in VGPRs
    const float4* Wi4 = (const float4*)(Wp + (size_t)unit * HID) + lane * 4;
    const float4* Wf4 = (const float4*)(Wp + (size_t)(unit + 1024) * HID) + lane * 4;
    const float4* Wg4 = (const float4*)(Wp + (size_t)(unit + 2048) * HID) + lane * 4;
    const float4* Wo4 = (const float4*)(Wp + (size_t)(unit + 3072) * HID) + lane * 4;
    float4 wi0 = Wi4[0], wi1 = Wi4[1], wi2 = Wi4[2], wi3 = Wi4[3];
    float4 wf0 = Wf4[0], wf1 = Wf4[1], wf2 = Wf4[2], wf3 = Wf4[3];
    float4 wg0 = Wg4[0], wg1 = Wg4[1], wg2 = Wg4[2], wg3 = Wg4[3];
    float4 wo0 = Wo4[0], wo1 = Wo4[1], wo2 = Wo4[2], wo3 = Wo4[3];

    const float bpi = bp[unit], bpf = bp[unit + 1024], bpg = bp[unit + 2048], bpo = bp[unit + 3072];
    const float gii = gi[unit], gif = gi[unit + 1024], gig = gi[unit + 2048], gio = gi[unit + 3072];

    __shared__ float hs[2][HID];

    float c = 0.f;

#pragma unroll 1
    for (int t = 1; t <= NSTEP; ++t) {
        float si, sf, sg, so;
        if (t == 1) {
            // h_0 = 0: gates are exactly ginit, no sync needed
            si = gii; sf = gif; sg = gig; so = gio;
        } else {
            const int slot = (t - 1) & 1;
            unsigned long long* src = hbuf + slot * HID + 2 * tid;
            const unsigned want = (unsigned)(t - 1);
            unsigned long long p0, p1;
            do {
                p0 = __hip_atomic_load(src,     __ATOMIC_RELAXED, __HIP_MEMORY_SCOPE_AGENT);
                p1 = __hip_atomic_load(src + 1, __ATOMIC_RELAXED, __HIP_MEMORY_SCOPE_AGENT);
            } while ((unsigned)(p0 >> 32) != want || (unsigned)(p1 >> 32) != want);
            float2 hv;
            hv.x = __uint_as_float((unsigned)p0);
            hv.y = __uint_as_float((unsigned)p1);
            *(float2*)&hs[slot][2 * tid] = hv;
            __syncthreads();

            const float4* h4 = (const float4*)&hs[slot][lane * 16];
            float4 h0 = h4[0], h1 = h4[1], h2 = h4[2], h3 = h4[3];
            si = d4(wi0, h0) + d4(wi1, h1) + d4(wi2, h2) + d4(wi3, h3);
            sf = d4(wf0, h0) + d4(wf1, h1) + d4(wf2, h2) + d4(wf3, h3);
            sg = d4(wg0, h0) + d4(wg1, h1) + d4(wg2, h2) + d4(wg3, h3);
            so = d4(wo0, h0) + d4(wo1, h1) + d4(wo2, h2) + d4(wo3, h3);
#pragma unroll
            for (int m = 32; m >= 1; m >>= 1) {
                si += __shfl_xor(si, m);
                sf += __shfl_xor(sf, m);
                sg += __shfl_xor(sg, m);
                so += __shfl_xor(so, m);
            }
            si += bpi; sf += bpf; sg += bpg; so += bpo;
        }

        // pointwise LSTM (replicated on all 64 lanes; c stays register-resident)
        float I = 1.f / (1.f + __expf(-si));
        float F = 1.f / (1.f + __expf(-sf));
        float G = 1.f - 2.f / (__expf(2.f * sg) + 1.f);   // tanh
        float O = 1.f / (1.f + __expf(-so));
        c = fmaf(F, c, I * G);
        float h = O * (1.f - 2.f / (__expf(2.f * c) + 1.f));

        if (lane == 0) {
            Hh[(size_t)(t - 1) * HID + unit] = h;  // history for decoder
            unsigned long long pair =
                ((unsigned long long)(unsigned)t << 32) | (unsigned long long)__float_as_uint(h);
            __hip_atomic_store(hbuf + (t & 1) * HID + unit, pair,
                               __ATOMIC_RELAXED, __HIP_MEMORY_SCOPE_AGENT);
        }
    }
}

// ---- decoder over the whole history: out[r][d] = W_dec[d] . H[r] + b_dec[d] ----
__global__ void k_dec(const float* __restrict__ Hh, const float* __restrict__ Wdec,
                      const float* __restrict__ bdec, float* __restrict__ out) {
    int idx = blockIdx.x * 256 + threadIdx.x;
    if (idx >= NSTEP * 11) return;
    int r = idx / 11, d = idx - r * 11;
    const float4* h4 = (const float4*)(Hh + (size_t)r * HID);
    const float4* w4 = (const float4*)(Wdec + (size_t)d * HID);
    float acc = 0.f;
#pragma unroll 4
    for (int k = 0; k < HID / 4; ++k) {
        float4 a = h4[k], b = w4[k];
        acc = fmaf(a.x, b.x, fmaf(a.y, b.y, fmaf(a.z, b.z, fmaf(a.w, b.w, acc))));
    }
    out[idx] = acc + bdec[d];
}

extern "C" void kernel_launch(void* const* d_in, const int* in_sizes, int n_in,
                              void* d_out, int out_size, void* d_ws, size_t ws_size,
                              hipStream_t stream) {
    const float* x    = (const float*)d_in[0];
    const float* Wih  = (const float*)d_in[1];
    const float* Whh  = (const float*)d_in[2];
    const float* bih  = (const float*)d_in[3];
    const float* bhh  = (const float*)d_in[4];
    const float* Wdec = (const float*)d_in[5];
    const float* bdec = (const float*)d_in[6];
    float* out = (float*)d_out;

    char* ws = (char*)d_ws;
    float* Wp = (float*)ws;                                   // 16 MiB
    float* bp = (float*)(ws + (16u << 20));                   // 16 KiB
    float* gi = bp + 4096;                                    // 16 KiB
    unsigned long long* hbuf = (unsigned long long*)(gi + 4096); // 16 KiB
    float* Hh = (float*)(ws + (16u << 20) + (64u << 10));     // 16 MiB

    k_prep<<<24, 256, 0, stream>>>(x, Wih, bih, bhh, bdec, bp, gi, hbuf);
    k_fold<<<(4096 * 1024) / 256, 256, 0, stream>>>(Wih, Whh, Wdec, Wp);
    lstm_seq<<<NBLK, THREADS, 0, stream>>>(Wp, bp, gi, hbuf, Hh);
    k_dec<<<(NSTEP * 11 + 255) / 256, 256, 0, stream>>>(Hh, Wdec, bdec, out);
}